// Round 1
// baseline (1094.680 us; speedup 1.0000x reference)
//
#include <hip/hip_runtime.h>
#include <hip/hip_bf16.h>

// MHA forward on MI355X (gfx950). All-bf16 MFMA compute, f32 accumulate.
// Pipeline: 3x proj GEMM (f32 in -> bf16 out) -> V transpose -> flash attn -> O-proj (f32 out).
// Constants from reference: B=8, NQ=NK=1024, D_MODEL=1024, H=16, DK=DV=64.

typedef unsigned short u16;
typedef __attribute__((ext_vector_type(8))) short short8;   // 8 bf16 = one MFMA A/B fragment
typedef __attribute__((ext_vector_type(4))) float float4v;  // MFMA C/D fragment

__device__ __forceinline__ u16 f2bf(float f) {
    unsigned int u = __float_as_uint(f);
    u = (u + 0x7fffu + ((u >> 16) & 1u)) >> 16;   // RNE
    return (u16)u;
}

// ---------------------------------------------------------------------------
// C[M=8192][N=1024] = A[8192][1024] @ W[1024][1024]^T + bias   (NT gemm)
// 128x128 block tile, BK=64, 4 waves each 64x64 via 4x4 mfma_16x16x32_bf16.
// ---------------------------------------------------------------------------
template <bool OUT_BF16>
__global__ __launch_bounds__(256) void proj_gemm(const float* __restrict__ A,
                                                 const float* __restrict__ W,
                                                 const float* __restrict__ bias,
                                                 void* __restrict__ C) {
    __shared__ __align__(16) u16 As[128][72];   // +8 pad: rows stay 16B aligned, breaks bank stride
    __shared__ __align__(16) u16 Bs[128][72];

    const int tid  = threadIdx.x;
    const int m0   = blockIdx.x * 128, n0 = blockIdx.y * 128;
    const int lane = tid & 63, w = tid >> 6;
    const int wm   = (w & 1) * 64, wn = (w >> 1) * 64;
    const int c    = lane & 15, quad = lane >> 4;

    const int lr = tid >> 4;          // staging row base 0..15
    const int lc = (tid & 15) * 4;    // staging col (f32 units) 0..60

    float4v acc[4][4] = {};

    for (int kb = 0; kb < 1024; kb += 64) {
#pragma unroll
        for (int i = 0; i < 8; ++i) {
            int row = lr + i * 16;
            float4 va = *(const float4*)&A[(size_t)(m0 + row) * 1024 + kb + lc];
            float4 vb = *(const float4*)&W[(size_t)(n0 + row) * 1024 + kb + lc];
            As[row][lc + 0] = f2bf(va.x); As[row][lc + 1] = f2bf(va.y);
            As[row][lc + 2] = f2bf(va.z); As[row][lc + 3] = f2bf(va.w);
            Bs[row][lc + 0] = f2bf(vb.x); Bs[row][lc + 1] = f2bf(vb.y);
            Bs[row][lc + 2] = f2bf(vb.z); Bs[row][lc + 3] = f2bf(vb.w);
        }
        __syncthreads();
#pragma unroll
        for (int ks = 0; ks < 2; ++ks) {
            short8 a[4], b[4];
#pragma unroll
            for (int i = 0; i < 4; ++i)
                a[i] = *(const short8*)&As[wm + i * 16 + c][ks * 32 + quad * 8];
#pragma unroll
            for (int i = 0; i < 4; ++i)
                b[i] = *(const short8*)&Bs[wn + i * 16 + c][ks * 32 + quad * 8];
#pragma unroll
            for (int i = 0; i < 4; ++i)
#pragma unroll
                for (int j = 0; j < 4; ++j)
                    acc[i][j] = __builtin_amdgcn_mfma_f32_16x16x32_bf16(a[i], b[j], acc[i][j], 0, 0, 0);
        }
        __syncthreads();
    }

    // epilogue: C/D layout col=lane&15, row=quad*4+reg  [m89/m91 verified]
#pragma unroll
    for (int j = 0; j < 4; ++j) {
        int n = n0 + wn + j * 16 + c;
        float bv = bias[n];
#pragma unroll
        for (int i = 0; i < 4; ++i) {
            int mb = m0 + wm + i * 16 + quad * 4;
#pragma unroll
            for (int r = 0; r < 4; ++r) {
                float v = acc[i][j][r] + bv;
                size_t off = (size_t)(mb + r) * 1024 + n;
                if (OUT_BF16) ((u16*)C)[off] = f2bf(v);
                else          ((float*)C)[off] = v;
            }
        }
    }
}

// ---------------------------------------------------------------------------
// Vt[bh][d][key] = Vb[b*1024+key][h*64+d]   (64-key tiles through LDS)
// ---------------------------------------------------------------------------
__global__ __launch_bounds__(256) void transpose_v(const u16* __restrict__ Vb,
                                                   u16* __restrict__ Vt) {
    __shared__ __align__(16) u16 t[64][72];
    const int bh = blockIdx.y, b = bh >> 4, h = bh & 15;
    const int k0 = blockIdx.x * 64;
    const int tid = threadIdx.x;
    {
        int key = tid >> 2, d0 = (tid & 3) << 4;
        const uint4* src = (const uint4*)&Vb[(size_t)(b * 1024 + k0 + key) * 1024 + h * 64 + d0];
        *(uint4*)&t[key][d0]     = src[0];
        *(uint4*)&t[key][d0 + 8] = src[1];
    }
    __syncthreads();
    {
        int d = tid & 63, kg = (tid >> 6) << 4;  // wave id picks key-group 0/16/32/48
        uint4 o[2];
        u16* op = (u16*)o;
#pragma unroll
        for (int i = 0; i < 16; ++i) op[i] = t[kg + i][d];
        uint4* dst = (uint4*)&Vt[((size_t)bh * 64 + d) * 1024 + k0 + kg];
        dst[0] = o[0];
        dst[1] = o[1];
    }
}

// ---------------------------------------------------------------------------
// Flash attention per (b,h): 64-row Q tile per block, 4 waves x 16 q-rows.
// S = Q K^T /8 * weights, causal mask, online softmax, O += P V.
// K / Vt fragments straight from global (L2-resident per head).
// ---------------------------------------------------------------------------
__global__ __launch_bounds__(256) void attn_kernel(const u16* __restrict__ Qb,
                                                   const u16* __restrict__ Kb,
                                                   const u16* __restrict__ Vt,
                                                   const float* __restrict__ Wts,
                                                   float* __restrict__ AO) {
    __shared__ __align__(16) u16 Plds[4][16][72];  // wave-private P tiles (16q x 64k)

    const int qt = blockIdx.x;          // q-tile 0..15
    const int bh = blockIdx.y;          // 0..127
    const int b  = bh >> 4, h = bh & 15;
    const int q0 = qt * 64;
    const int tid = threadIdx.x, lane = tid & 63, w = tid >> 6;
    const int c = lane & 15, quad = lane >> 4;
    const int qrow = q0 + w * 16;       // wave's 16 q-rows start

    // Q fragments: A-layout m=lane&15(q), k=quad*8+j(d); 2 k-steps cover DK=64
    short8 qf[2];
#pragma unroll
    for (int ks = 0; ks < 2; ++ks)
        qf[ks] = *(const short8*)&Qb[(size_t)(b * 1024 + qrow + c) * 1024 + h * 64 + ks * 32 + quad * 8];

    float m_run[4], l_run[4];
    float4v o[4] = {};
#pragma unroll
    for (int r = 0; r < 4; ++r) { m_run[r] = -1e30f; l_run[r] = 0.f; }

    for (int kt = 0; kt <= qt; ++kt) {
        const int k0 = kt * 64;
        // ---- S = Q K^T (4 key-tiles x 2 k-steps) ----
        float4v s[4] = {};
#pragma unroll
        for (int ks = 0; ks < 2; ++ks) {
#pragma unroll
            for (int t = 0; t < 4; ++t) {
                short8 kf = *(const short8*)&Kb[(size_t)(b * 1024 + k0 + t * 16 + c) * 1024 + h * 64 + ks * 32 + quad * 8];
                s[t] = __builtin_amdgcn_mfma_f32_16x16x32_bf16(qf[ks], kf, s[t], 0, 0, 0);
            }
        }
        // ---- scale * weights, causal mask (C layout: row q=quad*4+r, col key=t*16+c) ----
        const bool diag = (kt == qt);
        const float* wp = &Wts[((size_t)bh * 1024 + (qrow + quad * 4)) * 1024 + k0 + c];
#pragma unroll
        for (int t = 0; t < 4; ++t)
#pragma unroll
            for (int r = 0; r < 4; ++r) {
                float wv = wp[(size_t)r * 1024 + t * 16];
                float v = s[t][r] * 0.125f * wv;
                if (diag && (k0 + t * 16 + c) > (qrow + quad * 4 + r)) v = -1e30f;
                s[t][r] = v;
            }
        // ---- online softmax: rowmax over 64 keys (4 regs + shfl within 16-lane group) ----
        float alpha[4];
#pragma unroll
        for (int r = 0; r < 4; ++r) {
            float v = fmaxf(fmaxf(s[0][r], s[1][r]), fmaxf(s[2][r], s[3][r]));
#pragma unroll
            for (int off = 1; off < 16; off <<= 1) v = fmaxf(v, __shfl_xor(v, off, 64));
            float mn = fmaxf(m_run[r], v);
            alpha[r] = __expf(m_run[r] - mn);
            m_run[r] = mn;
        }
#pragma unroll
        for (int r = 0; r < 4; ++r) {
            float sum = 0.f;
#pragma unroll
            for (int t = 0; t < 4; ++t) {
                float p = __expf(s[t][r] - m_run[r]);
                s[t][r] = p;
                sum += p;
            }
#pragma unroll
            for (int off = 1; off < 16; off <<= 1) sum += __shfl_xor(sum, off, 64);
            l_run[r] = l_run[r] * alpha[r] + sum;
        }
        // ---- P: C-layout -> LDS -> A-layout (wave-private region) ----
#pragma unroll
        for (int t = 0; t < 4; ++t)
#pragma unroll
            for (int r = 0; r < 4; ++r)
                Plds[w][quad * 4 + r][t * 16 + c] = f2bf(s[t][r]);
        __syncthreads();   // all waves same trip count; orders LDS write->read
        // ---- rescale O, then O += P V ----
#pragma unroll
        for (int dt = 0; dt < 4; ++dt)
#pragma unroll
            for (int r = 0; r < 4; ++r) o[dt][r] *= alpha[r];
#pragma unroll
        for (int ks = 0; ks < 2; ++ks) {
            short8 pf = *(const short8*)&Plds[w][c][ks * 32 + quad * 8];
#pragma unroll
            for (int dt = 0; dt < 4; ++dt) {
                short8 vf = *(const short8*)&Vt[((size_t)bh * 64 + dt * 16 + c) * 1024 + k0 + ks * 32 + quad * 8];
                o[dt] = __builtin_amdgcn_mfma_f32_16x16x32_bf16(pf, vf, o[dt], 0, 0, 0);
            }
        }
        __syncthreads();
    }
    // ---- epilogue: AO[b*1024+q][h*64+d] = O / l ----
#pragma unroll
    for (int dt = 0; dt < 4; ++dt)
#pragma unroll
        for (int r = 0; r < 4; ++r) {
            float v = o[dt][r] / l_run[r];
            AO[(size_t)(b * 1024 + qrow + quad * 4 + r) * 1024 + h * 64 + dt * 16 + c] = v;
        }
}

// ---------------------------------------------------------------------------
extern "C" void kernel_launch(void* const* d_in, const int* in_sizes, int n_in,
                              void* d_out, int out_size, void* d_ws, size_t ws_size,
                              hipStream_t stream) {
    const float* q   = (const float*)d_in[0];
    const float* k   = (const float*)d_in[1];
    const float* v   = (const float*)d_in[2];
    const float* aw  = (const float*)d_in[3];
    // d_in[4] = attention_mask: fixed strict-upper-triangle causal -> computed analytically
    const float* Wq  = (const float*)d_in[5];
    const float* bq  = (const float*)d_in[6];
    const float* Wk  = (const float*)d_in[7];
    const float* bk  = (const float*)d_in[8];
    const float* Wv  = (const float*)d_in[9];
    const float* bv  = (const float*)d_in[10];
    const float* Wo  = (const float*)d_in[11];
    const float* bo  = (const float*)d_in[12];

    u16*   Qb = (u16*)d_ws;             // 8192x1024 bf16 = 16MB
    u16*   Kb = Qb + 8388608;           // 16MB
    u16*   Vb = Kb + 8388608;           // 16MB
    u16*   Vt = Vb + 8388608;           // 16MB  [bh][64][1024]
    float* AO = (float*)(Vt + 8388608); // 32MB  f32 attn output

    dim3 blk(256), pg(64, 8);
    proj_gemm<true><<<pg, blk, 0, stream>>>(q, Wq, bq, Qb);
    proj_gemm<true><<<pg, blk, 0, stream>>>(k, Wk, bk, Kb);
    proj_gemm<true><<<pg, blk, 0, stream>>>(v, Wv, bv, Vb);
    transpose_v<<<dim3(16, 128), blk, 0, stream>>>(Vb, Vt);
    attn_kernel<<<dim3(16, 128), blk, 0, stream>>>(Qb, Kb, Vt, aw, AO);
    proj_gemm<false><<<pg, blk, 0, stream>>>(AO, Wo, bo, (float*)d_out);
}

// Round 2
// 955.521 us; speedup vs baseline: 1.1456x; 1.1456x over previous
//
#include <hip/hip_runtime.h>

// MHA forward on MI355X (gfx950). bf16 MFMA compute, f32 accumulate.
// R2: bf16 pre-cast + m97-style global_load_lds GEMMs + LDS-staged flash attn.
// B=8, NQ=NK=1024, D_MODEL=1024, H=16, DK=DV=64.

typedef unsigned short u16;
typedef __attribute__((ext_vector_type(8))) short short8;   // 8 bf16 fragment
typedef __attribute__((ext_vector_type(4))) float float4v;  // MFMA C/D fragment

__device__ __forceinline__ u16 f2bf(float f) {
    unsigned int u = __float_as_uint(f);
    u = (u + 0x7fffu + ((u >> 16) & 1u)) >> 16;   // RNE
    return (u16)u;
}

__device__ __forceinline__ void glds16(const void* g, void* l) {
    __builtin_amdgcn_global_load_lds(
        (const __attribute__((address_space(1))) unsigned int*)g,
        (__attribute__((address_space(3))) unsigned int*)l, 16, 0, 0);
}

// ---------------------------------------------------------------------------
// f32 -> bf16 pre-cast: q,k,v (8.4M each) + Wq,Wk,Wv,Wo (1M each) into ws.
// ---------------------------------------------------------------------------
__global__ __launch_bounds__(256) void convert_bf16(const float* s0, const float* s1,
                                                    const float* s2, const float* s3,
                                                    const float* s4, const float* s5,
                                                    const float* s6, u16* base) {
    const size_t offs[7] = {0, 8388608, 16777216, 25165824, 26214400, 27262976, 28311552};
    const int    ns[7]   = {8388608, 8388608, 8388608, 1048576, 1048576, 1048576, 1048576};
    const float* srcs[7] = {s0, s1, s2, s3, s4, s5, s6};
    const int t = blockIdx.y;
    const float* src = srcs[t];
    u16* dst = base + offs[t];
    const int n8 = ns[t] >> 3;
    const int stride = gridDim.x * 256;
    for (int i = blockIdx.x * 256 + threadIdx.x; i < n8; i += stride) {
        float4 a = ((const float4*)src)[i * 2];
        float4 b = ((const float4*)src)[i * 2 + 1];
        uint4 o;
        o.x = (unsigned)f2bf(a.x) | ((unsigned)f2bf(a.y) << 16);
        o.y = (unsigned)f2bf(a.z) | ((unsigned)f2bf(a.w) << 16);
        o.z = (unsigned)f2bf(b.x) | ((unsigned)f2bf(b.y) << 16);
        o.w = (unsigned)f2bf(b.z) | ((unsigned)f2bf(b.w) << 16);
        ((uint4*)dst)[i] = o;
    }
}

// ---------------------------------------------------------------------------
// C[M][1024] = A[M][1024] @ W[1024][1024]^T + bias (NT), all-bf16, m97-style.
// 128x128 tile, BK=64, global_load_lds width=16, 4 waves x (64x64 via 4x4 mfma).
// blockIdx.z selects (A,W,bias,C) instance for fused QKV.
// ---------------------------------------------------------------------------
template <bool OUT_BF16>
__global__ __launch_bounds__(256) void gemm_bt(const u16* __restrict__ Ab,
                                               const u16* __restrict__ Wb,
                                               const float* b0, const float* b1,
                                               const float* b2, void* Cb,
                                               size_t Astride, size_t Wstride,
                                               size_t Cstride) {
    __shared__ __align__(16) u16 As[8192];   // 128 rows x 64 bf16 (128B rows, glds order)
    __shared__ __align__(16) u16 Bs[8192];

    const int z = blockIdx.z;
    const u16* A = Ab + (size_t)z * Astride;
    const u16* W = Wb + (size_t)z * Wstride;
    const float* bias = (z == 0) ? b0 : (z == 1) ? b1 : b2;

    const int m0 = blockIdx.x * 128, n0 = blockIdx.y * 128;
    const int tid = threadIdx.x, lane = tid & 63, w = tid >> 6;
    const int wm = (w & 1) * 64, wn = (w >> 1) * 64;
    const int c = lane & 15, quad = lane >> 4;
    const int srow = tid >> 3;          // 0..31
    const int scol = (tid & 7) * 8;     // bf16 col 0..56

    float4v acc[4][4] = {};

    for (int kb = 0; kb < 1024; kb += 64) {
#pragma unroll
        for (int i = 0; i < 4; ++i) {
            glds16(&A[(size_t)(m0 + i * 32 + srow) * 1024 + kb + scol], &As[i * 2048 + w * 512]);
            glds16(&W[(size_t)(n0 + i * 32 + srow) * 1024 + kb + scol], &Bs[i * 2048 + w * 512]);
        }
        __syncthreads();
#pragma unroll
        for (int ks = 0; ks < 2; ++ks) {
            short8 a[4], b[4];
#pragma unroll
            for (int i = 0; i < 4; ++i)
                a[i] = *(const short8*)&As[(wm + i * 16 + c) * 64 + ks * 32 + quad * 8];
#pragma unroll
            for (int j = 0; j < 4; ++j)
                b[j] = *(const short8*)&Bs[(wn + j * 16 + c) * 64 + ks * 32 + quad * 8];
#pragma unroll
            for (int i = 0; i < 4; ++i)
#pragma unroll
                for (int j = 0; j < 4; ++j)
                    acc[i][j] = __builtin_amdgcn_mfma_f32_16x16x32_bf16(a[i], b[j], acc[i][j], 0, 0, 0);
        }
        __syncthreads();
    }

    // C/D layout: col=lane&15, row=quad*4+reg
#pragma unroll
    for (int j = 0; j < 4; ++j) {
        int n = n0 + wn + j * 16 + c;
        float bv = bias[n];
#pragma unroll
        for (int i = 0; i < 4; ++i) {
            int mb = m0 + wm + i * 16 + quad * 4;
#pragma unroll
            for (int r = 0; r < 4; ++r) {
                float v = acc[i][j][r] + bv;
                size_t off = (size_t)(mb + r) * 1024 + n;
                if (OUT_BF16) ((u16*)Cb + (size_t)z * Cstride)[off] = f2bf(v);
                else          ((float*)Cb)[off] = v;
            }
        }
    }
}

// ---------------------------------------------------------------------------
// Vt[bh][d][key] = Vb[b*1024+key][h*64+d]
// ---------------------------------------------------------------------------
__global__ __launch_bounds__(256) void transpose_v(const u16* __restrict__ Vb,
                                                   u16* __restrict__ Vt) {
    __shared__ __align__(16) u16 t[64][72];
    const int bh = blockIdx.y, b = bh >> 4, h = bh & 15;
    const int k0 = blockIdx.x * 64;
    const int tid = threadIdx.x;
    {
        int key = tid >> 2, d0 = (tid & 3) << 4;
        const uint4* src = (const uint4*)&Vb[(size_t)(b * 1024 + k0 + key) * 1024 + h * 64 + d0];
        *(uint4*)&t[key][d0]     = src[0];
        *(uint4*)&t[key][d0 + 8] = src[1];
    }
    __syncthreads();
    {
        int d = tid & 63, kg = (tid >> 6) << 4;
        uint4 o[2];
        u16* op = (u16*)o;
#pragma unroll
        for (int i = 0; i < 16; ++i) op[i] = t[kg + i][d];
        uint4* dst = (uint4*)&Vt[((size_t)bh * 64 + d) * 1024 + k0 + kg];
        dst[0] = o[0];
        dst[1] = o[1];
    }
}

// ---------------------------------------------------------------------------
// Flash attention per (b,h): 64-q tile/block, 4 waves x 16 q-rows.
// K/Vt tiles staged in LDS via global_load_lds; weights hoisted; bf16 out.
// ---------------------------------------------------------------------------
__global__ __launch_bounds__(256) void attn_kernel(const u16* __restrict__ Qb,
                                                   const u16* __restrict__ Kb,
                                                   const u16* __restrict__ Vt,
                                                   const float* __restrict__ Wts,
                                                   u16* __restrict__ AO) {
    __shared__ __align__(16) u16 Ks[4096];      // 64 keys x 64 d (128B rows)
    __shared__ __align__(16) u16 Vs[4096];      // 64 d x 64 keys
    __shared__ __align__(16) u16 Pl[4][1024];   // wave-private 16q x 64k

    const int qt = blockIdx.x;
    const int bh = blockIdx.y;
    const int b = bh >> 4, h = bh & 15;
    const int q0 = qt * 64;
    const int tid = threadIdx.x, lane = tid & 63, w = tid >> 6;
    const int c = lane & 15, quad = lane >> 4;
    const int qrow = q0 + w * 16;
    const int srow = tid >> 3, scol = (tid & 7) * 8;

    short8 qf[2];
#pragma unroll
    for (int ks = 0; ks < 2; ++ks)
        qf[ks] = *(const short8*)&Qb[(size_t)(b * 1024 + qrow + c) * 1024 + h * 64 + ks * 32 + quad * 8];

    float m_run[4], l_run[4];
    float4v o[4] = {};
#pragma unroll
    for (int r = 0; r < 4; ++r) { m_run[r] = -1e30f; l_run[r] = 0.f; }

    for (int kt = 0; kt <= qt; ++kt) {
        const int k0 = kt * 64;
        // ---- stage K/Vt tiles (8KB each) ----
#pragma unroll
        for (int i = 0; i < 2; ++i) {
            glds16(&Kb[(size_t)(b * 1024 + k0 + i * 32 + srow) * 1024 + h * 64 + scol],
                   &Ks[i * 2048 + w * 512]);
            glds16(&Vt[((size_t)bh * 64 + i * 32 + srow) * 1024 + k0 + scol],
                   &Vs[i * 2048 + w * 512]);
        }
        // hoist weight loads (independent of LDS staging)
        float wv[4][4];
        const float* wp = &Wts[((size_t)bh * 1024 + (qrow + quad * 4)) * 1024 + k0 + c];
#pragma unroll
        for (int t = 0; t < 4; ++t)
#pragma unroll
            for (int r = 0; r < 4; ++r) wv[t][r] = wp[(size_t)r * 1024 + t * 16];
        __syncthreads();
        // ---- S = Q K^T ----
        float4v s[4] = {};
#pragma unroll
        for (int ks = 0; ks < 2; ++ks)
#pragma unroll
            for (int t = 0; t < 4; ++t) {
                short8 kf = *(const short8*)&Ks[(t * 16 + c) * 64 + ks * 32 + quad * 8];
                s[t] = __builtin_amdgcn_mfma_f32_16x16x32_bf16(qf[ks], kf, s[t], 0, 0, 0);
            }
        // ---- scale*weights + causal mask ----
        const bool diag = (kt == qt);
#pragma unroll
        for (int t = 0; t < 4; ++t)
#pragma unroll
            for (int r = 0; r < 4; ++r) {
                float v = s[t][r] * 0.125f * wv[t][r];
                if (diag && (k0 + t * 16 + c) > (qrow + quad * 4 + r)) v = -1e30f;
                s[t][r] = v;
            }
        // ---- online softmax ----
        float alpha[4];
#pragma unroll
        for (int r = 0; r < 4; ++r) {
            float v = fmaxf(fmaxf(s[0][r], s[1][r]), fmaxf(s[2][r], s[3][r]));
#pragma unroll
            for (int off = 1; off < 16; off <<= 1) v = fmaxf(v, __shfl_xor(v, off, 64));
            float mn = fmaxf(m_run[r], v);
            alpha[r] = __expf(m_run[r] - mn);
            m_run[r] = mn;
        }
#pragma unroll
        for (int r = 0; r < 4; ++r) {
            float sum = 0.f;
#pragma unroll
            for (int t = 0; t < 4; ++t) {
                float p = __expf(s[t][r] - m_run[r]);
                s[t][r] = p;
                sum += p;
            }
#pragma unroll
            for (int off = 1; off < 16; off <<= 1) sum += __shfl_xor(sum, off, 64);
            l_run[r] = l_run[r] * alpha[r] + sum;
        }
        // ---- P: C-layout -> wave-private LDS -> A-layout (same-wave DS ordering) ----
#pragma unroll
        for (int t = 0; t < 4; ++t)
#pragma unroll
            for (int r = 0; r < 4; ++r)
                Pl[w][(quad * 4 + r) * 64 + t * 16 + c] = f2bf(s[t][r]);
        // ---- rescale O, O += P V ----
#pragma unroll
        for (int dt = 0; dt < 4; ++dt)
#pragma unroll
            for (int r = 0; r < 4; ++r) o[dt][r] *= alpha[r];
#pragma unroll
        for (int ks = 0; ks < 2; ++ks) {
            short8 pf = *(const short8*)&Pl[w][c * 64 + ks * 32 + quad * 8];
#pragma unroll
            for (int dt = 0; dt < 4; ++dt) {
                short8 vf = *(const short8*)&Vs[(dt * 16 + c) * 64 + ks * 32 + quad * 8];
                o[dt] = __builtin_amdgcn_mfma_f32_16x16x32_bf16(pf, vf, o[dt], 0, 0, 0);
            }
        }
        __syncthreads();   // protect Ks/Vs restage
    }
    // ---- epilogue: AO bf16 ----
#pragma unroll
    for (int dt = 0; dt < 4; ++dt)
#pragma unroll
        for (int r = 0; r < 4; ++r)
            AO[(size_t)(b * 1024 + qrow + quad * 4 + r) * 1024 + h * 64 + dt * 16 + c] =
                f2bf(o[dt][r] / l_run[r]);
}

// ---------------------------------------------------------------------------
extern "C" void kernel_launch(void* const* d_in, const int* in_sizes, int n_in,
                              void* d_out, int out_size, void* d_ws, size_t ws_size,
                              hipStream_t stream) {
    const float* q  = (const float*)d_in[0];
    const float* k  = (const float*)d_in[1];
    const float* v  = (const float*)d_in[2];
    const float* aw = (const float*)d_in[3];
    // d_in[4] = attention_mask (fixed strict-upper causal; computed analytically)
    const float* bq = (const float*)d_in[6];
    const float* bk = (const float*)d_in[8];
    const float* bv = (const float*)d_in[10];
    const float* Wo = (const float*)d_in[11];
    const float* bo = (const float*)d_in[12];
    const float* Wq = (const float*)d_in[5];
    const float* Wk = (const float*)d_in[7];
    const float* Wv = (const float*)d_in[9];

    u16* ws16 = (u16*)d_ws;
    u16* qkvbf = ws16;                   // q,k,v bf16: 3 x 8388608
    u16* Wbf   = ws16 + 25165824;        // Wq,Wk,Wv,Wo bf16: 4 x 1048576
    u16* Wob   = ws16 + 28311552;
    u16* Qb    = ws16 + 29360128;        // Q,K,V projections: 3 x 8388608
    u16* Kb    = Qb + 8388608;
    u16* Vb    = Kb + 8388608;
    u16* Vt    = Vb + 8388608;           // [bh][64][1024]
    u16* AObf  = Vt + 8388608;           // attn output bf16

    dim3 blk(256);
    convert_bf16<<<dim3(512, 7), blk, 0, stream>>>(q, k, v, Wq, Wk, Wv, Wo, ws16);
    gemm_bt<true><<<dim3(64, 8, 3), blk, 0, stream>>>(qkvbf, Wbf, bq, bk, bv, Qb,
                                                      8388608, 1048576, 8388608);
    transpose_v<<<dim3(16, 128), blk, 0, stream>>>(Vb, Vt);
    attn_kernel<<<dim3(16, 128), blk, 0, stream>>>(Qb, Kb, Vt, aw, AObf);
    gemm_bt<false><<<dim3(64, 8, 1), blk, 0, stream>>>(AObf, Wob, bo, bo, bo, d_out,
                                                       0, 0, 0);
}